// Round 10
// baseline (138.075 us; speedup 1.0000x reference)
//
#include <hip/hip_runtime.h>

typedef __attribute__((ext_vector_type(8))) short bf16x8;
typedef __attribute__((ext_vector_type(4))) float f32x4;
typedef __attribute__((ext_vector_type(16))) float f32x16;
typedef __attribute__((ext_vector_type(4))) unsigned short u16x4;
typedef __attribute__((ext_vector_type(8))) unsigned short u16x8;

#define DIM 1024
#define SEQ 2048
#define NHEAD 16
#define HDIM 64
// 0.125 * log2(e): folds the 1/sqrt(64) scale into exp2 space
#define C2 0.18033688011112042f

__device__ __forceinline__ unsigned short f2bf(float f) {
  union { float f; unsigned u; } v; v.f = f;
  unsigned r = v.u + 0x7fffu + ((v.u >> 16) & 1u);
  return (unsigned short)(r >> 16);
}

__device__ __forceinline__ float bf2f(unsigned short s) {
  union { unsigned u; float f; } v; v.u = ((unsigned)s) << 16;
  return v.f;
}

__device__ __forceinline__ void gload_lds16(const void* g, void* l) {
  __builtin_amdgcn_global_load_lds(
      (const __attribute__((address_space(1))) void*)g,
      (__attribute__((address_space(3))) void*)l, 16, 0, 0);
}

__device__ __forceinline__ f32x16 mfma32(bf16x8 a, bf16x8 b, f32x16 c) {
  return __builtin_amdgcn_mfma_f32_32x32x16_bf16(a, b, c, 0, 0, 0);
}

__device__ __forceinline__ unsigned cvtpk(float lo, float hi) {
  unsigned r;
  asm("v_cvt_pk_bf16_f32 %0, %1, %2" : "=v"(r) : "v"(lo), "v"(hi));
  return r;
}

// ---------------- fused fp32 -> bf16 conversion (x + 4 weights) ----------------
__global__ void f2bf_all(const float* __restrict__ x, const float* __restrict__ wq,
                         const float* __restrict__ wk, const float* __restrict__ wv,
                         const float* __restrict__ wo, unsigned short* __restrict__ xb,
                         unsigned short* __restrict__ wb) {
  int blk = blockIdx.x;
  const float* src;
  unsigned short* dst;
  int rb;
  if (blk < 4096) { src = x; dst = xb; rb = blk; }
  else {
    int w = (blk - 4096) >> 10;
    src = w == 0 ? wq : w == 1 ? wk : w == 2 ? wv : wo;
    dst = wb + (size_t)w * 1048576;
    rb = (blk - 4096) & 1023;
  }
  int i = rb * 256 + threadIdx.x;  // float4 index
  float4 v = ((const float4*)src)[i];
  u16x4 o;
  o[0] = f2bf(v.x); o[1] = f2bf(v.y); o[2] = f2bf(v.z); o[3] = f2bf(v.w);
  ((u16x4*)dst)[i] = o;
}

// ---------------- fused Q/K/VT projection GEMM, one launch, dbuf prefetch -----
// 768 blocks, XCD-aligned. [0,512): Q,K: C[token][dim] = x @ w^T ;
// [512,768): VT: C[dim_v][token] = wv @ x^T. Q pre-scaled by C2.
__global__ __launch_bounds__(256) void gemm3(
    const unsigned short* __restrict__ xb,
    const unsigned short* __restrict__ wb,
    unsigned short* __restrict__ qkv) {
  __shared__ unsigned short As[2][8192];
  __shared__ unsigned short Bs[2][8192];
  const int bz = blockIdx.x;
  const unsigned short *A, *B;
  unsigned short* C;
  int m0, n0, ldc;
  float cscale = 1.0f;
  if (bz < 512) {
    int xcd = bz & 7, inner = bz >> 3;
    int mm = inner & 3, n = (inner >> 2) & 7, w = inner >> 5;
    m0 = (xcd * 4 + mm) * 128; n0 = n * 128;
    A = xb; B = wb + w * 1048576; C = qkv + w * 4194304; ldc = 1024;
    if (w == 0) cscale = C2;
  } else {
    int idx = bz - 512;
    int xcd = idx & 7, inner = idx >> 3;
    int tt = inner & 3, mv = inner >> 2;
    m0 = mv * 128; n0 = (xcd * 4 + tt) * 128;
    A = wb + 2 * 1048576; B = xb; C = qkv + 2 * 4194304; ldc = 4096;
  }
  const int tid = threadIdx.x;
  const int wv = tid >> 6, lane = tid & 63;
  const int g = lane >> 4, l16 = lane & 15;
  const int wm = (wv >> 1) * 64, wn = (wv & 1) * 64;
  f32x4 acc[4][4] = {};

#define GSTAGE(IT, BUF)                                                        \
  {                                                                            \
    const int kt = (IT) * 64;                                                  \
    _Pragma("unroll")                                                          \
    for (int qq = 0; qq < 4; ++qq) {                                           \
      int rbase = wv * 32 + qq * 8;                                            \
      int r = rbase + (lane >> 3);                                             \
      int cs = ((lane & 7) ^ (r & 7)) * 8;                                     \
      gload_lds16(A + (long long)(m0 + r) * 1024 + kt + cs,                    \
                  &As[BUF][rbase * 64]);                                       \
      gload_lds16(B + (long long)(n0 + r) * 1024 + kt + cs,                    \
                  &Bs[BUF][rbase * 64]);                                       \
    }                                                                          \
  }

  GSTAGE(0, 0);
  __syncthreads();

  for (int it = 0; it < 16; ++it) {
    const int buf = it & 1;
    if (it + 1 < 16) GSTAGE(it + 1, buf ^ 1);
#pragma unroll
    for (int ks = 0; ks < 2; ++ks) {
      bf16x8 af[4], bfr[4];
      const int cb = ks * 64 + g * 16;
#pragma unroll
      for (int mf = 0; mf < 4; ++mf) {
        int row = wm + mf * 16 + l16;
        af[mf] = *(const bf16x8*)((const char*)&As[buf][0] + row * 128 + (cb ^ ((row & 7) << 4)));
      }
#pragma unroll
      for (int nf = 0; nf < 4; ++nf) {
        int row = wn + nf * 16 + l16;
        bfr[nf] = *(const bf16x8*)((const char*)&Bs[buf][0] + row * 128 + (cb ^ ((row & 7) << 4)));
      }
#pragma unroll
      for (int mf = 0; mf < 4; ++mf)
#pragma unroll
        for (int nf = 0; nf < 4; ++nf)
          acc[mf][nf] = __builtin_amdgcn_mfma_f32_16x16x32_bf16(
              af[mf], bfr[nf], acc[mf][nf], 0, 0, 0);
    }
    __syncthreads();  // drains prefetch (vmcnt 0) + guards buffer reuse
  }

#pragma unroll
  for (int mf = 0; mf < 4; ++mf)
#pragma unroll
    for (int nf = 0; nf < 4; ++nf)
#pragma unroll
      for (int r = 0; r < 4; ++r) {
        long long m = m0 + wm + mf * 16 + g * 4 + r;
        long long n = n0 + wn + nf * 16 + l16;
        C[m * ldc + n] = f2bf(acc[mf][nf][r] * cscale);
      }
}

// ---------------- NT GEMM (f32 out) for the output projection, dbuf prefetch --
__global__ __launch_bounds__(256) void gemm_out(
    const unsigned short* __restrict__ A,
    const unsigned short* __restrict__ B,
    float* __restrict__ C) {
  __shared__ unsigned short As[2][8192];
  __shared__ unsigned short Bs[2][8192];
  const int tid = threadIdx.x;
  const int wv = tid >> 6, lane = tid & 63;
  const int g = lane >> 4, l16 = lane & 15;
  const int m0 = blockIdx.y * 128, n0 = blockIdx.x * 128;
  const int wm = (wv >> 1) * 64, wn = (wv & 1) * 64;
  f32x4 acc[4][4] = {};

#define OSTAGE(IT, BUF)                                                        \
  {                                                                            \
    const int kt = (IT) * 64;                                                  \
    _Pragma("unroll")                                                          \
    for (int qq = 0; qq < 4; ++qq) {                                           \
      int rbase = wv * 32 + qq * 8;                                            \
      int r = rbase + (lane >> 3);                                             \
      int cs = ((lane & 7) ^ (r & 7)) * 8;                                     \
      gload_lds16(A + (long long)(m0 + r) * 1024 + kt + cs,                    \
                  &As[BUF][rbase * 64]);                                       \
      gload_lds16(B + (long long)(n0 + r) * 1024 + kt + cs,                    \
                  &Bs[BUF][rbase * 64]);                                       \
    }                                                                          \
  }

  OSTAGE(0, 0);
  __syncthreads();

  for (int it = 0; it < 16; ++it) {
    const int buf = it & 1;
    if (it + 1 < 16) OSTAGE(it + 1, buf ^ 1);
#pragma unroll
    for (int ks = 0; ks < 2; ++ks) {
      bf16x8 af[4], bfr[4];
      const int cb = ks * 64 + g * 16;
#pragma unroll
      for (int mf = 0; mf < 4; ++mf) {
        int row = wm + mf * 16 + l16;
        af[mf] = *(const bf16x8*)((const char*)&As[buf][0] + row * 128 + (cb ^ ((row & 7) << 4)));
      }
#pragma unroll
      for (int nf = 0; nf < 4; ++nf) {
        int row = wn + nf * 16 + l16;
        bfr[nf] = *(const bf16x8*)((const char*)&Bs[buf][0] + row * 128 + (cb ^ ((row & 7) << 4)));
      }
#pragma unroll
      for (int mf = 0; mf < 4; ++mf)
#pragma unroll
        for (int nf = 0; nf < 4; ++nf)
          acc[mf][nf] = __builtin_amdgcn_mfma_f32_16x16x32_bf16(
              af[mf], bfr[nf], acc[mf][nf], 0, 0, 0);
    }
    __syncthreads();
  }

#pragma unroll
  for (int mf = 0; mf < 4; ++mf)
#pragma unroll
    for (int nf = 0; nf < 4; ++nf)
#pragma unroll
      for (int r = 0; r < 4; ++r) {
        long long m = m0 + wm + mf * 16 + g * 4 + r;
        long long n = n0 + wn + nf * 16 + l16;
        C[m * 1024 + n] = acc[mf][nf][r];
      }
}

// ---------------- flash attention: 256-row q-tiles, 4 waves x 64 rows ----------
// Per (b,h): q-tile qt8 in [0,8) (256 rows), nt = 4qt8+4 k-tiles, chunks of <=8:
// cn = (qt8+2)>>1 -> 20 chunks/(b,h) -> grid (20,16,2) = 640 blocks. Each wave
// computes TWO 32-row sub-tiles (nf=0,1) per staged 64-key tile -> 2x compute per
// staged byte vs round 9. Fixed-reference softmax: Q pre-scaled by C2, p=exp2(s)
// (normalization cancels any fixed reference). cn==1 writes O direct; else
// unnormalized partials (bf16 acc + f32 l), summed by attn_merge.
// Partial slot s<256 lives in the dead xb buffer; rest after ao.
__global__ __launch_bounds__(256, 2) void attn_kernel(
    const unsigned short* __restrict__ Qg,
    const unsigned short* __restrict__ Kg,
    const unsigned short* __restrict__ VTg,
    unsigned short* __restrict__ Og,
    unsigned short* __restrict__ pacc1,
    unsigned short* __restrict__ pacc2,
    float* __restrict__ pml) {
  __shared__ unsigned short Kls[2][4096];  // [buf][key 64][d 64] (chunk-swizzled)
  __shared__ unsigned short Vls[2][4096];  // [buf][d 64][key 64] (chunk-swizzled)

  const int tid = threadIdx.x;
  const int wv = tid >> 6, lane = tid & 63;
  const int l32 = lane & 31, hi = lane >> 5;
  const int h = blockIdx.y, b = blockIdx.z;

  // chunk decode (LPT: 16 8-tile chunks first, then 4 4-tile chunks)
  const int i = blockIdx.x;  // [0,20)
  int qt8, c;
  if (i < 4)        { qt8 = 7; c = i; }
  else if (i < 7)   { qt8 = 6; c = i - 4; }
  else if (i < 10)  { qt8 = 5; c = i - 7; }
  else if (i < 12)  { qt8 = 4; c = i - 10; }
  else if (i < 14)  { qt8 = 3; c = i - 12; }
  else if (i == 14) { qt8 = 2; c = 0; }
  else if (i == 15) { qt8 = 1; c = 0; }
  else if (i == 16) { qt8 = 6; c = 3; }
  else if (i == 17) { qt8 = 4; c = 2; }
  else if (i == 18) { qt8 = 2; c = 1; }
  else              { qt8 = 0; c = 0; }
  const int cn = (qt8 + 2) >> 1;

  const int nt = 4 * qt8 + 4;
  const int t0 = c * 8;
  const int tb = min(t0 + 8, nt);                  // block stage bound
  const int tw = min(tb, 4 * qt8 + wv + 1);        // wave compute bound (both nf)

  const int q0 = qt8 * 256 + wv * 64 + l32;        // nf=0 q row
  const int q1 = q0 + 32;                          // nf=1 q row
  const long long bh = (long long)b * SEQ * DIM + h * HDIM;
  const long long vbase = (long long)h * HDIM * 4096 + b * SEQ;

  // Q fragments (B-operand) for both sub-tiles
  const unsigned short* Qrow0 = Qg + (long long)(b * SEQ + q0) * DIM + h * HDIM;
  const unsigned short* Qrow1 = Qg + (long long)(b * SEQ + q1) * DIM + h * HDIM;
  bf16x8 qf0[4], qf1[4];
#pragma unroll
  for (int ds = 0; ds < 4; ++ds) {
    qf0[ds] = *(const bf16x8*)(Qrow0 + ds * 16 + hi * 8);
    qf1[ds] = *(const bf16x8*)(Qrow1 + ds * 16 + hi * 8);
  }

  f32x16 acc00 = {}, acc01 = {};   // nf=0: dblk 0,1
  f32x16 acc10 = {}, acc11 = {};   // nf=1
  float l0 = 0.f, l1 = 0.f;

  // stage: wave wv loads K chunks {2wv,2wv+1} and V chunks {2wv,2wv+1}
  const int sr = lane >> 3, sc = lane & 7;
#define STAGE(T, BUF)                                                          \
  {                                                                            \
    const int kv0s = (T) * 64;                                                 \
    _Pragma("unroll")                                                          \
    for (int s = 0; s < 2; ++s) {                                              \
      int jj = wv * 2 + s;                                                     \
      int r = jj * 8 + sr;                                                     \
      int cs = (sc ^ (r & 7)) * 8;                                             \
      gload_lds16(Kg + bh + (long long)(kv0s + r) * DIM + cs,                  \
                  &Kls[BUF][jj * 512]);                                        \
      gload_lds16(VTg + vbase + (long long)r * 4096 + kv0s + cs,               \
                  &Vls[BUF][jj * 512]);                                        \
    }                                                                          \
  }

// one 32-row sub-tile: QK^T -> mask -> exp2 -> l -> P->bf16 -> PV
#define NF_TILE(QF, QROW, ACCA, ACCB, LRUN)                                    \
  {                                                                            \
    f32x16 s0 = {}, s1 = {};                                                   \
    __builtin_amdgcn_s_setprio(1);                                             \
    _Pragma("unroll")                                                          \
    for (int ds = 0; ds < 4; ++ds) {                                           \
      const int cb = (((ds << 1) | hi) ^ (l32 & 7)) * 16;                      \
      bf16x8 k0 = *(const bf16x8*)((const char*)&Kls[buf][0] + l32 * 128 + cb);\
      bf16x8 k1 = *(const bf16x8*)((const char*)&Kls[buf][0] + (32 + l32) * 128 + cb); \
      s0 = mfma32(k0, (QF)[ds], s0);                                           \
      s1 = mfma32(k1, (QF)[ds], s1);                                           \
    }                                                                          \
    __builtin_amdgcn_s_setprio(0);                                             \
    if (kv0 + 64 > (QROW)) {                                                   \
      _Pragma("unroll")                                                        \
      for (int r = 0; r < 16; ++r) {                                           \
        int kw = (r & 3) + 8 * (r >> 2) + 4 * hi;                              \
        if (kv0 + kw > (QROW)) s0[r] = -1e30f;                                 \
        if (kv0 + 32 + kw > (QROW)) s1[r] = -1e30f;                            \
      }                                                                        \
    }                                                                          \
    float at[16];                                                              \
    _Pragma("unroll")                                                          \
    for (int r = 0; r < 16; ++r) {                                             \
      float p0 = exp2f(s0[r]);                                                 \
      float p1 = exp2f(s1[r]);                                                 \
      s0[r] = p0; s1[r] = p1;                                                  \
      at[r] = p0 + p1;                                                         \
    }                                                                          \
    _Pragma("unroll")                                                          \
    for (int off = 8; off; off >>= 1)                                          \
      _Pragma("unroll")                                                        \
      for (int i2 = 0; i2 < off; ++i2) at[i2] += at[i2 + off];                 \
    (LRUN) += at[0] + __shfl_xor(at[0], 32);                                   \
    __builtin_amdgcn_s_setprio(1);                                             \
    _Pragma("unroll")                                                          \
    for (int kks = 0; kks < 4; ++kks) {                                        \
      const int base2 = (kks & 1) * 8;                                         \
      unsigned a0, a1, a2, a3;                                                 \
      if (kks < 2) {                                                           \
        a0 = cvtpk(s0[base2 + 0], s0[base2 + 1]);                              \
        a1 = cvtpk(s0[base2 + 2], s0[base2 + 3]);                              \
        a2 = cvtpk(s0[base2 + 4], s0[base2 + 5]);                              \
        a3 = cvtpk(s0[base2 + 6], s0[base2 + 7]);                              \
      } else {                                                                 \
        a0 = cvtpk(s1[base2 + 0], s1[base2 + 1]);                              \
        a1 = cvtpk(s1[base2 + 2], s1[base2 + 3]);                              \
        a2 = cvtpk(s1[base2 + 4], s1[base2 + 5]);                              \
        a3 = cvtpk(s1[base2 + 6], s1[base2 + 7]);                              \
      }                                                                        \
      asm("v_permlane32_swap_b32 %0, %1" : "+v"(a0), "+v"(a2));                \
      asm("v_permlane32_swap_b32 %0, %1" : "+v"(a1), "+v"(a3));                \
      union { unsigned u[4]; bf16x8 v; } pf;                                   \
      pf.u[0] = a0; pf.u[1] = a1; pf.u[2] = a2; pf.u[3] = a3;                  \
      const int cb = (((kks << 1) | hi) ^ (l32 & 7)) * 16;                     \
      bf16x8 v0 = *(const bf16x8*)((const char*)&Vls[buf][0] + l32 * 128 + cb);\
      bf16x8 v1 = *(const bf16x8*)((const char*)&Vls[buf][0] + (32 + l32) * 128 + cb); \
      (ACCA) = mfma32(v0, pf.v, (ACCA));                                       \
      (ACCB) = mfma32(v1, pf.v, (ACCB));                                       \
    }                                                                          \
    __builtin_amdgcn_s_setprio(0);                                             \
  }

  STAGE(t0, 0);
  __syncthreads();

  for (int t = t0; t < tb; ++t) {
    const int buf = (t - t0) & 1;
    if (t + 1 < tb) STAGE(t + 1, buf ^ 1);

    if (t < tw) {
      const int kv0 = t * 64;
      NF_TILE(qf0, q0, acc00, acc01, l0);
      NF_TILE(qf1, q1, acc10, acc11, l1);
    }
    __syncthreads();  // drains prefetch (vmcnt 0) + guards buffer reuse
  }

#define WRITE_O(ACCA, ACCB, QROW, LV)                                          \
  {                                                                            \
    const float inv_l = 1.0f / (LV);                                           \
    unsigned short* Orow = Og + (long long)(b * SEQ + (QROW)) * DIM + h * HDIM;\
    _Pragma("unroll")                                                          \
    for (int dblk = 0; dblk < 2; ++dblk) {                                     \
      _Pragma("unroll")                                                        \
      for (int g4 = 0; g4 < 4; ++g4) {                                         \
        u16x4 o;                                                               \
        _Pragma("unroll")                                                      \
        for (int jv = 0; jv < 4; ++jv) {                                       \
          float v = (dblk ? (ACCB)[g4 * 4 + jv] : (ACCA)[g4 * 4 + jv]) * inv_l;\
          o[jv] = f2bf(v);                                                     \
        }                                                                      \
        *(u16x4*)(Orow + dblk * 32 + 8 * g4 + 4 * hi) = o;                     \
      }                                                                        \
    }                                                                          \
  }

#define WRITE_P(ACCA, ACCB, ROWL)                                              \
  {                                                                            \
    unsigned short* pbase = sp + (size_t)(ROWL) * 64;                          \
    _Pragma("unroll")                                                          \
    for (int dblk = 0; dblk < 2; ++dblk) {                                     \
      _Pragma("unroll")                                                        \
      for (int g4 = 0; g4 < 4; ++g4) {                                         \
        u16x4 o;                                                               \
        _Pragma("unroll")                                                      \
        for (int jv = 0; jv < 4; ++jv)                                         \
          o[jv] = f2bf(dblk ? (ACCB)[g4 * 4 + jv] : (ACCA)[g4 * 4 + jv]);      \
        *(u16x4*)(pbase + dblk * 32 + 8 * g4 + 4 * hi) = o;                    \
      }                                                                        \
    }                                                                          \
  }

  if (cn == 1) {
    WRITE_O(acc00, acc01, q0, l0);
    WRITE_O(acc10, acc11, q1, l1);
  } else {
    const int sb = qt8 == 2 ? 0 : qt8 == 3 ? 2 : qt8 == 4 ? 4
                 : qt8 == 5 ? 7 : qt8 == 6 ? 10 : 14;
    const int slot = (b * NHEAD + h) * 18 + sb + c;
    unsigned short* sp = (slot < 256) ? pacc1 + (size_t)slot * 16384
                                      : pacc2 + (size_t)(slot - 256) * 16384;
    WRITE_P(acc00, acc01, wv * 64 + l32);
    WRITE_P(acc10, acc11, wv * 64 + 32 + l32);
    if (hi == 0) {
      pml[slot * 256 + wv * 64 + l32] = l0;
      pml[slot * 256 + wv * 64 + 32 + l32] = l1;
    }
  }
}

// ---------------- split-K merge: plain sum of 2-4 partials per (b,h,qt8>=2) ---
__global__ __launch_bounds__(256) void attn_merge(
    const unsigned short* __restrict__ pacc1,
    const unsigned short* __restrict__ pacc2,
    const float* __restrict__ pml,
    unsigned short* __restrict__ Og) {
  const int qt8 = 2 + blockIdx.x;  // 2..7
  const int h = blockIdx.y, b = blockIdx.z;
  const int cn = (qt8 + 2) >> 1;
  const int sb = qt8 == 2 ? 0 : qt8 == 3 ? 2 : qt8 == 4 ? 4
               : qt8 == 5 ? 7 : qt8 == 6 ? 10 : 14;
  const int base_slot = (b * NHEAD + h) * 18 + sb;
  const int t = threadIdx.x;

#pragma unroll
  for (int rr = 0; rr < 2; ++rr) {
    const int row = rr * 128 + (t >> 1);
    const int d0 = (t & 1) * 32;

    float L = 0.f;
#pragma unroll
    for (int cc = 0; cc < 4; ++cc)
      if (cc < cn) L += pml[(base_slot + cc) * 256 + row];
    const float invL = 1.0f / L;

    float o[32] = {};
#pragma unroll
    for (int cc = 0; cc < 4; ++cc)
      if (cc < cn) {
        const int s = base_slot + cc;
        const unsigned short* p =
            ((s < 256) ? pacc1 + (size_t)s * 16384
                       : pacc2 + (size_t)(s - 256) * 16384) + (size_t)row * 64 + d0;
#pragma unroll
        for (int k = 0; k < 32; k += 8) {
          u16x8 v = *(const u16x8*)(p + k);
#pragma unroll
          for (int jv = 0; jv < 8; ++jv) o[k + jv] += bf2f(v[jv]);
        }
      }

    const int q = qt8 * 256 + row;
    unsigned short* orow = Og + (size_t)(b * SEQ + q) * DIM + h * HDIM + d0;
#pragma unroll
    for (int k = 0; k < 32; k += 8) {
      u16x8 ov;
#pragma unroll
      for (int jv = 0; jv < 8; ++jv) ov[jv] = f2bf(o[k + jv] * invL);
      *(u16x8*)(orow + k) = ov;
    }
  }
}

// ---------------- launcher ----------------
extern "C" void kernel_launch(void* const* d_in, const int* in_sizes, int n_in,
                              void* d_out, int out_size, void* d_ws, size_t ws_size,
                              hipStream_t stream) {
  const float* x   = (const float*)d_in[0];
  const float* wq  = (const float*)d_in[2];
  const float* wk  = (const float*)d_in[3];
  const float* wv_ = (const float*)d_in[4];
  const float* wo  = (const float*)d_in[5];

  unsigned short* xb  = (unsigned short*)d_ws;            // [4096][1024]; reused as pacc1 after gemm3
  unsigned short* wb  = xb + (size_t)4096 * 1024;         // [4][1024][1024] q,k,v,o
  unsigned short* qkv = wb + (size_t)4 * 1024 * 1024;     // Q,K [4096][1024]; VT [1024][4096]
  unsigned short* ao  = qkv + (size_t)3 * 4096 * 1024;    // [4096][1024]
  unsigned short* pacc2 = ao + (size_t)4096 * 1024;       // partial slots 256..575 (32 KB each)
  float* pml = (float*)(pacc2 + (size_t)320 * 16384);     // [576][256] f32 l

  f2bf_all<<<8192, 256, 0, stream>>>(x, wq, wk, wv_, wo, xb, wb);

  // Q, K, V^T projections in ONE launch (768 blocks); Q pre-scaled by C2
  gemm3<<<768, 256, 0, stream>>>(xb, wb, qkv);

  attn_kernel<<<dim3(20, 16, 2), 256, 0, stream>>>(
      qkv, qkv + 4194304, qkv + 2 * 4194304, ao, xb, pacc2, pml);

  attn_merge<<<dim3(6, 16, 2), 256, 0, stream>>>(xb, pacc2, pml, ao);

  // output projection -> fp32 d_out
  gemm_out<<<dim3(8, 32, 1), 256, 0, stream>>>(ao, wb + 3145728, (float*)d_out);
}

// Round 11
// 125.056 us; speedup vs baseline: 1.1041x; 1.1041x over previous
//
#include <hip/hip_runtime.h>

typedef __attribute__((ext_vector_type(8))) short bf16x8;
typedef __attribute__((ext_vector_type(4))) float f32x4;
typedef __attribute__((ext_vector_type(16))) float f32x16;
typedef __attribute__((ext_vector_type(4))) unsigned short u16x4;
typedef __attribute__((ext_vector_type(8))) unsigned short u16x8;

#define DIM 1024
#define SEQ 2048
#define NHEAD 16
#define HDIM 64
// 0.125 * log2(e): folds the 1/sqrt(64) scale into exp2 space
#define C2 0.18033688011112042f

__device__ __forceinline__ unsigned short f2bf(float f) {
  union { float f; unsigned u; } v; v.f = f;
  unsigned r = v.u + 0x7fffu + ((v.u >> 16) & 1u);
  return (unsigned short)(r >> 16);
}

__device__ __forceinline__ float bf2f(unsigned short s) {
  union { unsigned u; float f; } v; v.u = ((unsigned)s) << 16;
  return v.f;
}

__device__ __forceinline__ void gload_lds16(const void* g, void* l) {
  __builtin_amdgcn_global_load_lds(
      (const __attribute__((address_space(1))) void*)g,
      (__attribute__((address_space(3))) void*)l, 16, 0, 0);
}

__device__ __forceinline__ f32x16 mfma32(bf16x8 a, bf16x8 b, f32x16 c) {
  return __builtin_amdgcn_mfma_f32_32x32x16_bf16(a, b, c, 0, 0, 0);
}

__device__ __forceinline__ unsigned cvtpk(float lo, float hi) {
  unsigned r;
  asm("v_cvt_pk_bf16_f32 %0, %1, %2" : "=v"(r) : "v"(lo), "v"(hi));
  return r;
}

// ---------------- fused fp32 -> bf16 conversion (x + 4 weights) ----------------
__global__ void f2bf_all(const float* __restrict__ x, const float* __restrict__ wq,
                         const float* __restrict__ wk, const float* __restrict__ wv,
                         const float* __restrict__ wo, unsigned short* __restrict__ xb,
                         unsigned short* __restrict__ wb) {
  int blk = blockIdx.x;
  const float* src;
  unsigned short* dst;
  int rb;
  if (blk < 4096) { src = x; dst = xb; rb = blk; }
  else {
    int w = (blk - 4096) >> 10;
    src = w == 0 ? wq : w == 1 ? wk : w == 2 ? wv : wo;
    dst = wb + (size_t)w * 1048576;
    rb = (blk - 4096) & 1023;
  }
  int i = rb * 256 + threadIdx.x;  // float4 index
  float4 v = ((const float4*)src)[i];
  u16x4 o;
  o[0] = f2bf(v.x); o[1] = f2bf(v.y); o[2] = f2bf(v.z); o[3] = f2bf(v.w);
  ((u16x4*)dst)[i] = o;
}

// ---------------- fused Q/K/VT projection GEMM, one launch, dbuf prefetch -----
// 768 blocks, XCD-aligned. [0,512): Q,K: C[token][dim] = x @ w^T ;
// [512,768): VT: C[dim_v][token] = wv @ x^T. Q pre-scaled by C2.
__global__ __launch_bounds__(256) void gemm3(
    const unsigned short* __restrict__ xb,
    const unsigned short* __restrict__ wb,
    unsigned short* __restrict__ qkv) {
  __shared__ unsigned short As[2][8192];
  __shared__ unsigned short Bs[2][8192];
  const int bz = blockIdx.x;
  const unsigned short *A, *B;
  unsigned short* C;
  int m0, n0, ldc;
  float cscale = 1.0f;
  if (bz < 512) {
    int xcd = bz & 7, inner = bz >> 3;
    int mm = inner & 3, n = (inner >> 2) & 7, w = inner >> 5;
    m0 = (xcd * 4 + mm) * 128; n0 = n * 128;
    A = xb; B = wb + w * 1048576; C = qkv + w * 4194304; ldc = 1024;
    if (w == 0) cscale = C2;
  } else {
    int idx = bz - 512;
    int xcd = idx & 7, inner = idx >> 3;
    int tt = inner & 3, mv = inner >> 2;
    m0 = mv * 128; n0 = (xcd * 4 + tt) * 128;
    A = wb + 2 * 1048576; B = xb; C = qkv + 2 * 4194304; ldc = 4096;
  }
  const int tid = threadIdx.x;
  const int wv = tid >> 6, lane = tid & 63;
  const int g = lane >> 4, l16 = lane & 15;
  const int wm = (wv >> 1) * 64, wn = (wv & 1) * 64;
  f32x4 acc[4][4] = {};

#define GSTAGE(IT, BUF)                                                        \
  {                                                                            \
    const int kt = (IT) * 64;                                                  \
    _Pragma("unroll")                                                          \
    for (int qq = 0; qq < 4; ++qq) {                                           \
      int rbase = wv * 32 + qq * 8;                                            \
      int r = rbase + (lane >> 3);                                             \
      int cs = ((lane & 7) ^ (r & 7)) * 8;                                     \
      gload_lds16(A + (long long)(m0 + r) * 1024 + kt + cs,                    \
                  &As[BUF][rbase * 64]);                                       \
      gload_lds16(B + (long long)(n0 + r) * 1024 + kt + cs,                    \
                  &Bs[BUF][rbase * 64]);                                       \
    }                                                                          \
  }

  GSTAGE(0, 0);
  __syncthreads();

  for (int it = 0; it < 16; ++it) {
    const int buf = it & 1;
    if (it + 1 < 16) GSTAGE(it + 1, buf ^ 1);
#pragma unroll
    for (int ks = 0; ks < 2; ++ks) {
      bf16x8 af[4], bfr[4];
      const int cb = ks * 64 + g * 16;
#pragma unroll
      for (int mf = 0; mf < 4; ++mf) {
        int row = wm + mf * 16 + l16;
        af[mf] = *(const bf16x8*)((const char*)&As[buf][0] + row * 128 + (cb ^ ((row & 7) << 4)));
      }
#pragma unroll
      for (int nf = 0; nf < 4; ++nf) {
        int row = wn + nf * 16 + l16;
        bfr[nf] = *(const bf16x8*)((const char*)&Bs[buf][0] + row * 128 + (cb ^ ((row & 7) << 4)));
      }
#pragma unroll
      for (int mf = 0; mf < 4; ++mf)
#pragma unroll
        for (int nf = 0; nf < 4; ++nf)
          acc[mf][nf] = __builtin_amdgcn_mfma_f32_16x16x32_bf16(
              af[mf], bfr[nf], acc[mf][nf], 0, 0, 0);
    }
    __syncthreads();  // drains prefetch (vmcnt 0) + guards buffer reuse
  }

#pragma unroll
  for (int mf = 0; mf < 4; ++mf)
#pragma unroll
    for (int nf = 0; nf < 4; ++nf)
#pragma unroll
      for (int r = 0; r < 4; ++r) {
        long long m = m0 + wm + mf * 16 + g * 4 + r;
        long long n = n0 + wn + nf * 16 + l16;
        C[m * ldc + n] = f2bf(acc[mf][nf][r] * cscale);
      }
}

// ---------------- NT GEMM (f32 out) for the output projection, dbuf prefetch --
__global__ __launch_bounds__(256) void gemm_out(
    const unsigned short* __restrict__ A,
    const unsigned short* __restrict__ B,
    float* __restrict__ C) {
  __shared__ unsigned short As[2][8192];
  __shared__ unsigned short Bs[2][8192];
  const int tid = threadIdx.x;
  const int wv = tid >> 6, lane = tid & 63;
  const int g = lane >> 4, l16 = lane & 15;
  const int m0 = blockIdx.y * 128, n0 = blockIdx.x * 128;
  const int wm = (wv >> 1) * 64, wn = (wv & 1) * 64;
  f32x4 acc[4][4] = {};

#define OSTAGE(IT, BUF)                                                        \
  {                                                                            \
    const int kt = (IT) * 64;                                                  \
    _Pragma("unroll")                                                          \
    for (int qq = 0; qq < 4; ++qq) {                                           \
      int rbase = wv * 32 + qq * 8;                                            \
      int r = rbase + (lane >> 3);                                             \
      int cs = ((lane & 7) ^ (r & 7)) * 8;                                     \
      gload_lds16(A + (long long)(m0 + r) * 1024 + kt + cs,                    \
                  &As[BUF][rbase * 64]);                                       \
      gload_lds16(B + (long long)(n0 + r) * 1024 + kt + cs,                    \
                  &Bs[BUF][rbase * 64]);                                       \
    }                                                                          \
  }

  OSTAGE(0, 0);
  __syncthreads();

  for (int it = 0; it < 16; ++it) {
    const int buf = it & 1;
    if (it + 1 < 16) OSTAGE(it + 1, buf ^ 1);
#pragma unroll
    for (int ks = 0; ks < 2; ++ks) {
      bf16x8 af[4], bfr[4];
      const int cb = ks * 64 + g * 16;
#pragma unroll
      for (int mf = 0; mf < 4; ++mf) {
        int row = wm + mf * 16 + l16;
        af[mf] = *(const bf16x8*)((const char*)&As[buf][0] + row * 128 + (cb ^ ((row & 7) << 4)));
      }
#pragma unroll
      for (int nf = 0; nf < 4; ++nf) {
        int row = wn + nf * 16 + l16;
        bfr[nf] = *(const bf16x8*)((const char*)&Bs[buf][0] + row * 128 + (cb ^ ((row & 7) << 4)));
      }
#pragma unroll
      for (int mf = 0; mf < 4; ++mf)
#pragma unroll
        for (int nf = 0; nf < 4; ++nf)
          acc[mf][nf] = __builtin_amdgcn_mfma_f32_16x16x32_bf16(
              af[mf], bfr[nf], acc[mf][nf], 0, 0, 0);
    }
    __syncthreads();
  }

#pragma unroll
  for (int mf = 0; mf < 4; ++mf)
#pragma unroll
    for (int nf = 0; nf < 4; ++nf)
#pragma unroll
      for (int r = 0; r < 4; ++r) {
        long long m = m0 + wm + mf * 16 + g * 4 + r;
        long long n = n0 + wn + nf * 16 + l16;
        C[m * 1024 + n] = acc[mf][nf][r];
      }
}

// ---------------- flash attention, split-K, fixed-ref softmax, 32-key subtiles --
// Round 9 structure (4 waves / 128-row q-tile, 40 chunks/(b,h), grid (40,16,2)),
// register-dieted: each 64-key tile processed as two 32-key sub-tiles reusing ONE
// s[16] score set; softmax denominator accumulated via ones-MFMA (lacc) instead of
// a VALU tree; launch_bounds(256,4) forces <=128 regs -> 4 waves/SIMD.
// Sub-tile u=2t+s computed iff u <= umax = 4qt+wv (uniform per wave); u==umax is
// the diagonal (mask iff key-within-32 kw > l32).
__global__ __launch_bounds__(256, 4) void attn_kernel(
    const unsigned short* __restrict__ Qg,
    const unsigned short* __restrict__ Kg,
    const unsigned short* __restrict__ VTg,
    unsigned short* __restrict__ Og,
    unsigned short* __restrict__ pacc,
    float* __restrict__ pml) {
  __shared__ unsigned short Kls[2][4096];  // [buf][key 64][d 64] (chunk-swizzled)
  __shared__ unsigned short Vls[2][4096];  // [buf][d 64][key 64] (chunk-swizzled)

  const int tid = threadIdx.x;
  const int wv = tid >> 6, lane = tid & 63;
  const int l32 = lane & 31, hi = lane >> 5;
  const int h = blockIdx.y, b = blockIdx.z;

  // chunk decode, longest-qt first (LPT)
  const int i = blockIdx.x;  // [0,40)
  int qt, c, cn;
  if (i < 16)      { qt = 15 - (i >> 2); c = i & 3; cn = 4; }
  else if (i < 28) { int j = i - 16; qt = 11 - j / 3; c = j % 3; cn = 3; }
  else if (i < 36) { int j = i - 28; qt = 7 - ((j >> 1)); c = j & 1; cn = 2; }
  else             { qt = 39 - i; c = 0; cn = 1; }

  const int nt = 2 * qt + 2;
  const int t0 = c * 8;
  const int tb = min(t0 + 8, nt);   // block stage bound
  const int umax = 4 * qt + wv;     // last 32-key sub-tile this wave computes

  const int q = qt * 128 + wv * 32 + l32;
  const long long bh = (long long)b * SEQ * DIM + h * HDIM;
  const long long vbase = (long long)h * HDIM * 4096 + b * SEQ;

  // Q fragments (B-operand): B[col=q][k = hi*8+j], per 16-d slice
  const unsigned short* Qrow = Qg + (long long)(b * SEQ + q) * DIM + h * HDIM;
  bf16x8 qf[4];
#pragma unroll
  for (int ds = 0; ds < 4; ++ds)
    qf[ds] = *(const bf16x8*)(Qrow + ds * 16 + hi * 8);

  // all-ones bf16 A-fragment for the l-accumulating MFMA
  bf16x8 ones;
#pragma unroll
  for (int j = 0; j < 8; ++j) ones[j] = (short)0x3F80;

  f32x16 acc0 = {}, acc1 = {}, lacc = {};

  // stage: wave wv loads K chunks {2wv,2wv+1} and V chunks {2wv,2wv+1}
  // (chunk j = 8 rows of 128 B; linear LDS dest, inverse-swizzled global source)
  const int sr = lane >> 3, sc = lane & 7;
#define STAGE(T, BUF)                                                          \
  {                                                                            \
    const int kv0s = (T) * 64;                                                 \
    _Pragma("unroll")                                                          \
    for (int s = 0; s < 2; ++s) {                                              \
      int jj = wv * 2 + s;                                                     \
      int r = jj * 8 + sr;                                                     \
      int cs = (sc ^ (r & 7)) * 8;                                             \
      gload_lds16(Kg + bh + (long long)(kv0s + r) * DIM + cs,                  \
                  &Kls[BUF][jj * 512]);                                        \
      gload_lds16(VTg + vbase + (long long)r * 4096 + kv0s + cs,               \
                  &Vls[BUF][jj * 512]);                                        \
    }                                                                          \
  }

  STAGE(t0, 0);
  __syncthreads();

  for (int t = t0; t < tb; ++t) {
    const int buf = (t - t0) & 1;
    if (t + 1 < tb) STAGE(t + 1, buf ^ 1);

#pragma unroll
    for (int s = 0; s < 2; ++s) {
      const int u = 2 * t + s;
      if (u <= umax) {
        // --- QK^T for 32 keys (windowed K reads) ---
        f32x16 sv = {};
        __builtin_amdgcn_s_setprio(1);
#pragma unroll
        for (int ds = 0; ds < 4; ++ds) {
          const int cbk = (((ds << 1) | hi) ^ (l32 & 7)) * 16;
          bf16x8 kf = *(const bf16x8*)((const char*)&Kls[buf][0] +
                                       (s * 32 + l32) * 128 + cbk);
          sv = mfma32(kf, qf[ds], sv);
        }
        __builtin_amdgcn_s_setprio(0);

        // --- causal mask (only the diagonal sub-tile; key base == q base) ---
        if (u == umax) {
#pragma unroll
          for (int r = 0; r < 16; ++r) {
            int kw = (r & 3) + 8 * (r >> 2) + 4 * hi;  // key within 32-block
            if (kw > l32) sv[r] = -1e30f;
          }
        }

        // --- p = exp2(s) (fixed reference; normalization cancels) ---
#pragma unroll
        for (int r = 0; r < 16; ++r) sv[r] = exp2f(sv[r]);

        // --- P -> bf16 B-fragments (in-register) + PV + l via ones-MFMA ---
        __builtin_amdgcn_s_setprio(1);
#pragma unroll
        for (int kk = 0; kk < 2; ++kk) {
          const int base = kk * 8;
          unsigned a0 = cvtpk(sv[base + 0], sv[base + 1]);
          unsigned a1 = cvtpk(sv[base + 2], sv[base + 3]);
          unsigned a2 = cvtpk(sv[base + 4], sv[base + 5]);
          unsigned a3 = cvtpk(sv[base + 6], sv[base + 7]);
          asm("v_permlane32_swap_b32 %0, %1" : "+v"(a0), "+v"(a2));
          asm("v_permlane32_swap_b32 %0, %1" : "+v"(a1), "+v"(a3));
          union { unsigned u4[4]; bf16x8 v; } pf;
          pf.u4[0] = a0; pf.u4[1] = a1; pf.u4[2] = a2; pf.u4[3] = a3;
          const int slice = 2 * s + kk;  // 16-key slice within the 64-key tile
          const int cbv = (((slice << 1) | hi) ^ (l32 & 7)) * 16;
          bf16x8 v0 = *(const bf16x8*)((const char*)&Vls[buf][0] + l32 * 128 + cbv);
          bf16x8 v1 = *(const bf16x8*)((const char*)&Vls[buf][0] + (32 + l32) * 128 + cbv);
          acc0 = mfma32(v0, pf.v, acc0);
          acc1 = mfma32(v1, pf.v, acc1);
          lacc = mfma32(ones, pf.v, lacc);
        }
        __builtin_amdgcn_s_setprio(0);
      }
    }
    __syncthreads();  // drains prefetch (vmcnt 0) + guards buffer reuse
  }

  const float l_run = lacc[0];  // every row of lacc holds the column sum l(q)

  if (cn == 1) {
    // --- direct epilogue: O[b, q, h*64 + d] = acc^T / l ---
    const float inv_l = 1.0f / l_run;
    unsigned short* Orow = Og + (long long)(b * SEQ + q) * DIM + h * HDIM;
#pragma unroll
    for (int dblk = 0; dblk < 2; ++dblk) {
#pragma unroll
      for (int g4 = 0; g4 < 4; ++g4) {
        u16x4 o;
#pragma unroll
        for (int jv = 0; jv < 4; ++jv) {
          float v = (dblk ? acc1[g4 * 4 + jv] : acc0[g4 * 4 + jv]) * inv_l;
          o[jv] = f2bf(v);
        }
        *(u16x4*)(Orow + dblk * 32 + 8 * g4 + 4 * hi) = o;
      }
    }
  } else {
    // --- partial epilogue: unnormalized acc (bf16) + l (f32) ---
    const int sbase = qt < 8 ? 2 * (qt - 4) : qt < 12 ? 8 + 3 * (qt - 8) : 20 + 4 * (qt - 12);
    const int slot = (b * NHEAD + h) * 36 + sbase + c;
    unsigned short* pbase = pacc + (size_t)slot * 8192 + (wv * 32 + l32) * 64;
#pragma unroll
    for (int dblk = 0; dblk < 2; ++dblk) {
#pragma unroll
      for (int g4 = 0; g4 < 4; ++g4) {
        u16x4 o;
#pragma unroll
        for (int jv = 0; jv < 4; ++jv)
          o[jv] = f2bf(dblk ? acc1[g4 * 4 + jv] : acc0[g4 * 4 + jv]);
        *(u16x4*)(pbase + dblk * 32 + 8 * g4 + 4 * hi) = o;
      }
    }
    if (hi == 0) pml[slot * 128 + wv * 32 + l32] = l_run;
  }
}

// ---------------- split-K merge: plain sum (fixed reference => weights 1) ----
__global__ __launch_bounds__(256) void attn_merge(
    const unsigned short* __restrict__ pacc,
    const float* __restrict__ pml,
    unsigned short* __restrict__ Og) {
  const int qt = 4 + blockIdx.x;  // 4..15
  const int h = blockIdx.y, b = blockIdx.z;
  const int cn = (qt >> 2) + 1;
  const int sbase = qt < 8 ? 2 * (qt - 4) : qt < 12 ? 8 + 3 * (qt - 8) : 20 + 4 * (qt - 12);
  const int base_slot = (b * NHEAD + h) * 36 + sbase;
  const int t = threadIdx.x;
  const int ql = t >> 1, d0 = (t & 1) * 32;

  float L = 0.f;
#pragma unroll
  for (int cc = 0; cc < 4; ++cc)
    if (cc < cn) L += pml[(base_slot + cc) * 128 + ql];
  const float invL = 1.0f / L;

  float o[32] = {};
#pragma unroll
  for (int cc = 0; cc < 4; ++cc)
    if (cc < cn) {
      const unsigned short* p = pacc + (size_t)(base_slot + cc) * 8192 + ql * 64 + d0;
#pragma unroll
      for (int k = 0; k < 32; k += 8) {
        u16x8 v = *(const u16x8*)(p + k);
#pragma unroll
        for (int jv = 0; jv < 8; ++jv) o[k + jv] += bf2f(v[jv]);
      }
    }

  const int q = qt * 128 + ql;
  unsigned short* orow = Og + (size_t)(b * SEQ + q) * DIM + h * HDIM + d0;
#pragma unroll
  for (int k = 0; k < 32; k += 8) {
    u16x8 ov;
#pragma unroll
    for (int jv = 0; jv < 8; ++jv) ov[jv] = f2bf(o[k + jv] * invL);
    *(u16x8*)(orow + k) = ov;
  }
}

// ---------------- launcher ----------------
extern "C" void kernel_launch(void* const* d_in, const int* in_sizes, int n_in,
                              void* d_out, int out_size, void* d_ws, size_t ws_size,
                              hipStream_t stream) {
  const float* x   = (const float*)d_in[0];
  const float* wq  = (const float*)d_in[2];
  const float* wk  = (const float*)d_in[3];
  const float* wv_ = (const float*)d_in[4];
  const float* wo  = (const float*)d_in[5];

  unsigned short* xb  = (unsigned short*)d_ws;            // [4096][1024]
  unsigned short* wb  = xb + (size_t)4096 * 1024;         // [4][1024][1024] q,k,v,o
  unsigned short* qkv = wb + (size_t)4 * 1024 * 1024;     // Q,K [4096][1024]; VT [1024][4096]
  unsigned short* ao  = qkv + (size_t)3 * 4096 * 1024;    // [4096][1024]
  unsigned short* pacc = ao + (size_t)4096 * 1024;        // [1152][128][64] bf16 partial acc
  float* pml = (float*)(pacc + (size_t)1152 * 8192);      // [1152][128] f32 l

  f2bf_all<<<8192, 256, 0, stream>>>(x, wq, wk, wv_, wo, xb, wb);

  // Q, K, V^T projections in ONE launch (768 blocks); Q pre-scaled by C2
  gemm3<<<768, 256, 0, stream>>>(xb, wb, qkv);

  attn_kernel<<<dim3(40, 16, 2), 256, 0, stream>>>(
      qkv, qkv + 4194304, qkv + 2 * 4194304, ao, pacc, pml);

  attn_merge<<<dim3(12, 16, 2), 256, 0, stream>>>(pacc, pml, ao);

  // output projection -> fp32 d_out
  gemm_out<<<dim3(8, 32, 1), 256, 0, stream>>>(ao, wb + 3145728, (float*)d_out);
}